// Round 19
// baseline (263.697 us; speedup 1.0000x reference)
//
#include <hip/hip_runtime.h>
#include <hip/hip_bf16.h>

#define BATCH 4
#define CIN 64
#define HH 352
#define WW 1216
#define OCH 8
#define OHH 354
#define OWW 1218
#define HW (HH * WW)

#define BH 16       // output rows per block (4 waves x 4 rows)
#define BW 32       // output cols per block
#define FC 34       // staged cols (halo)
#define WROWS 6     // input rows staged per wave (4 out + 2 halo)
#define WPOS (WROWS * FC)   // 204 positions per wave
#define WSLOT (WPOS * 4)    // 816 16B-slots per wave
#define NTHR 256
#define GX 38            // WW/BW
#define GY 22            // HH/BH
#define NWG (GX * GY * BATCH)   // 3344 = 8 * 418
#define CPX (NWG / 8)           // 418 blocks per XCD

typedef short bf16x8 __attribute__((ext_vector_type(8)));
typedef float f32x4  __attribute__((ext_vector_type(4)));

// fp32 -> bf16 round-to-nearest-even (branchless, finite inputs)
static __device__ __forceinline__ unsigned f2bf(float x) {
    unsigned u = __float_as_uint(x);
    return (u + 0x7FFFu + ((u >> 16) & 1u)) >> 16;
}

// Bake weights into exact MFMA B-fragment layout (bf16, BN-folded, oc>=8 zero):
// wB[(tap*2+cc)*64 + lane] = 8 bf16: B[k = hi*8+j][col = oc], k-channel = cc*32+hi*8+j
__global__ void repack_kernel(const float* __restrict__ conv_w,
                              const float* __restrict__ gamma,
                              const float* __restrict__ beta,
                              const float* __restrict__ mean,
                              const float* __restrict__ var,
                              unsigned short* __restrict__ wB,
                              float* __restrict__ bias)
{
    int tid = blockIdx.x * 256 + threadIdx.x;
    if (tid < 18 * 64) {
        int tc = tid >> 6;          // tap*2 + cc
        int lane = tid & 63;
        int tap = tc >> 1, cc = tc & 1;
        int oc = lane & 15, hi = lane >> 4;
        unsigned v[8];
#pragma unroll
        for (int j = 0; j < 8; ++j) {
            float w = 0.f;
            if (oc < 8) {
                int c = cc * 32 + hi * 8 + j;
                float scl = gamma[oc] * rsqrtf(var[oc] + 1e-5f);
                w = conv_w[((size_t)oc * CIN + c) * 9 + tap] * scl;
            }
            v[j] = f2bf(w);
        }
        uint4 pk;
        pk.x = v[0] | (v[1] << 16);
        pk.y = v[2] | (v[3] << 16);
        pk.z = v[4] | (v[5] << 16);
        pk.w = v[6] | (v[7] << 16);
        ((uint4*)wB)[tid] = pk;
    }
    if (tid < OCH) {
        float scl = gamma[tid] * rsqrtf(var[tid] + 1e-5f);
        bias[tid] = beta[tid] - mean[tid] * scl;
    }
}

// Zero only the uncovered border ring of each (b,t) OUTPUT plane.
__global__ void border_kernel(float* __restrict__ out)
{
    const int bt = blockIdx.x;          // 0..35
    const int t = bt % 9;
    const int i = t / 3, j = t % 3;
    float* pl = out + (size_t)bt * OHH * OWW;
    const int r0 = (i == 0) ? HH : 0;
    const int r1 = (i == 2) ? 1 : (OHH - 1);
    const int c0 = (j == 0) ? WW : 0;
    const int c1 = (j == 2) ? 1 : (OWW - 1);
    const int nrow = 2 * OWW;
    for (int idx = threadIdx.x; idx < 2 * OWW + 2 * OHH; idx += blockDim.x) {
        if (idx < nrow) {
            int r = (idx < OWW) ? r0 : r1;
            int c = (idx < OWW) ? idx : idx - OWW;
            pl[(size_t)r * OWW + c] = 0.f;
        } else {
            int k = idx - nrow;
            int c = (k < OHH) ? c0 : c1;
            int r = (k < OHH) ? k : k - OHH;
            pl[(size_t)r * OWW + c] = 0.f;
        }
    }
}

// One register-lean staging pass: NP tasks, 8 strided loads each, pack bf16, ds_write.
#define STAGE_PASS(Q0, NP) { \
    float v[NP][8]; float mk[NP]; int sl[NP]; \
    _Pragma("unroll") for (int k = 0; k < NP; ++k) { \
        int pos = p0 + (Q0 + k) * 16; \
        pos = (pos < WPOS) ? pos : (WPOS - 1);          /* tail: benign duplicate */ \
        int lr = pos / FC; int fc = pos - lr * FC; \
        int gh = h0w - 1 + lr, gw = w0 - 1 + fc; \
        bool ok = ((unsigned)gh < (unsigned)HH) && ((unsigned)gw < (unsigned)WW); \
        int sgh = min(max(gh, 0), HH - 1); \
        int sgw = min(max(gw, 0), WW - 1); \
        const float* sp = chbase + sgh * WW + sgw; \
        _Pragma("unroll") for (int j = 0; j < 8; ++j) v[k][j] = sp[(size_t)j * HW]; \
        mk[k] = ok ? 1.f : 0.f; \
        sl[k] = wslot0 + pos * 4 + (soct ^ ((pos >> 1) & 3)); \
    } \
    _Pragma("unroll") for (int k = 0; k < NP; ++k) { \
        float m_ = mk[k]; uint4 pk; \
        pk.x = f2bf(v[k][0] * m_) | (f2bf(v[k][1] * m_) << 16); \
        pk.y = f2bf(v[k][2] * m_) | (f2bf(v[k][3] * m_) << 16); \
        pk.z = f2bf(v[k][4] * m_) | (f2bf(v[k][5] * m_) << 16); \
        pk.w = f2bf(v[k][6] * m_) | (f2bf(v[k][7] * m_) << 16); \
        sF[sl[k]] = pk; \
    } }

__global__ __launch_bounds__(NTHR, 2)   // no tighter cap: forced caps spill (r3/r14/r15)
void conv_mfma(const float* __restrict__ feature,
               const unsigned short* __restrict__ wB,
               const float* __restrict__ bias,
               float* __restrict__ out)
{
    // Wave-PRIVATE staged tiles: wave w owns sF[w*WSLOT .. (w+1)*WSLOT).
    // No cross-wave sharing -> ZERO __syncthreads in the kernel; waves
    // self-pipeline (some staging while others MFMA). DS returns are in-order
    // within a wave, so chunk-0 reads complete before chunk-1 writes issue.
    __shared__ uint4 sF[4 * WSLOT];   // 52224 B

    // Bijective XCD swizzle (nwg = 3344 = 8*418): FETCH 707 -> 320 MB (r14/r16).
    const int lin = blockIdx.x;
    const int wg  = (lin & 7) * CPX + (lin >> 3);
    const int bx  = wg % GX;
    const int byz = wg / GX;
    const int by  = byz % GY;
    const int b   = byz / GY;

    const int tid  = threadIdx.x;
    const int wave = tid >> 6;
    const int lane = tid & 63;
    const int oc   = lane & 15;
    const int hi   = lane >> 4;
    const int h0 = by * BH;
    const int w0 = bx * BW;
    const int h0w = h0 + wave * 4;          // this wave's first output row
    const int wslot0 = wave * WSLOT;        // this wave's LDS base (uint4 idx)

    const float* fb = feature + (size_t)b * CIN * HW;
    const int soct = lane & 3;              // slot stride 64 ≡ 0 mod 4 -> oct fixed
    const int p0   = lane >> 2;             // 0..15

    f32x4 acc[4][2];
#pragma unroll
    for (int rr = 0; rr < 4; ++rr)
#pragma unroll
        for (int cg = 0; cg < 2; ++cg) acc[rr][cg] = (f32x4)0.f;

#pragma unroll 1
    for (int cc = 0; cc < 2; ++cc) {
        const float* chbase = fb + (size_t)(cc * 32 + soct * 8) * HW;

        // 13 tasks in register-lean passes (5/4/4): buffer 40 regs max.
        STAGE_PASS(0, 5)
        STAGE_PASS(5, 4)
        STAGE_PASS(9, 4)

        // B-fragments after staging (L2-resident 18KB): keeps peak pressure low.
        bf16x8 bwl[9];
#pragma unroll
        for (int t = 0; t < 9; ++t)
            bwl[t] = ((const bf16x8*)wB)[(t * 2 + cc) * 64 + lane];

#pragma unroll
        for (int t = 0; t < 9; ++t) {
            const int dh = t / 3, dw = t % 3;
#pragma unroll
            for (int rr = 0; rr < 4; ++rr) {
                const int lr = rr + dh;         // wave-local staged row 0..5
#pragma unroll
                for (int cg = 0; cg < 2; ++cg) {
                    const int fc = cg * 16 + oc + dw;
                    const int pp = lr * FC + fc;
                    bf16x8 av = *reinterpret_cast<const bf16x8*>(
                        &sF[wslot0 + pp * 4 + (hi ^ ((pp >> 1) & 3))]);
                    acc[rr][cg] = __builtin_amdgcn_mfma_f32_16x16x32_bf16(av, bwl[t], acc[rr][cg], 0, 0, 0);
                }
            }
        }
    }

    // ---- epilogue: bias, L1-normalize across oc (16-lane shfl), mid, scatter ----
    const float myb = (oc < 8) ? bias[oc] : 0.f;
    const int t = (oc < 8) ? ((oc < 4) ? oc : oc + 1) : 4;
    const bool dow = (oc <= 8);
    const int ii = t / 3, jj = t % 3;
    float* pl = out + ((size_t)(b * 9 + t) * OHH + ii) * OWW + jj;

#pragma unroll
    for (int rr = 0; rr < 4; ++rr) {
        const int h = h0w + rr;
#pragma unroll
        for (int cg = 0; cg < 2; ++cg) {
#pragma unroll
            for (int reg = 0; reg < 4; ++reg) {
                float vv = acc[rr][cg][reg] + myb;   // lanes oc>=8: 0
                float av = fabsf(vv);
                float sv = vv;
                av += __shfl_xor(av, 1);  sv += __shfl_xor(sv, 1);
                av += __shfl_xor(av, 2);  sv += __shfl_xor(sv, 2);
                av += __shfl_xor(av, 4);  sv += __shfl_xor(sv, 4);
                av += __shfl_xor(av, 8);  sv += __shfl_xor(sv, 8);
                float inv = 1.0f / av;
                float val = (oc == 8) ? (1.0f - sv * inv) : (vv * inv);
                if (dow) {
                    int w = w0 + cg * 16 + hi * 4 + reg;
                    pl[(size_t)h * OWW + w] = val;
                }
            }
        }
    }
}

extern "C" void kernel_launch(void* const* d_in, const int* in_sizes, int n_in,
                              void* d_out, int out_size, void* d_ws, size_t ws_size,
                              hipStream_t stream) {
    const float* feature = (const float*)d_in[0];
    const float* conv_w  = (const float*)d_in[1];
    const float* gamma   = (const float*)d_in[2];
    const float* beta    = (const float*)d_in[3];
    const float* mean    = (const float*)d_in[4];
    const float* var     = (const float*)d_in[5];
    float* out = (float*)d_out;

    unsigned short* wB = (unsigned short*)d_ws;    // 18432 B
    float* bias = (float*)((char*)d_ws + 18432);   // 32 B

    border_kernel<<<BATCH * 9, 256, 0, stream>>>(out);
    repack_kernel<<<5, 256, 0, stream>>>(conv_w, gamma, beta, mean, var, wB, bias);
    conv_mfma<<<NWG, NTHR, 0, stream>>>(feature, wB, bias, out);
}

// Round 21
// 225.130 us; speedup vs baseline: 1.1713x; 1.1713x over previous
//
#include <hip/hip_runtime.h>
#include <hip/hip_bf16.h>

#define BATCH 4
#define CIN 64
#define HH 352
#define WW 1216
#define OCH 8
#define OHH 354
#define OWW 1218
#define HW (HH * WW)

#define BH 16       // output rows per block
#define BW 32       // output cols per block
#define FR 18       // staged rows (halo)
#define FC 34       // staged cols (halo)
#define NPOS (FR * FC)   // 612
#define NTHR 256
#define NIT 10           // staging tasks per thread (block-shared tile)
#define GX 38            // WW/BW
#define GY 22            // HH/BH
#define NWG (GX * GY * BATCH)   // 3344 = 8 * 418
#define CPX (NWG / 8)           // 418 blocks per XCD

typedef short bf16x8 __attribute__((ext_vector_type(8)));
typedef float f32x4  __attribute__((ext_vector_type(4)));

// fp32 -> bf16 round-to-nearest-even (branchless, finite inputs)
static __device__ __forceinline__ unsigned f2bf(float x) {
    unsigned u = __float_as_uint(x);
    return (u + 0x7FFFu + ((u >> 16) & 1u)) >> 16;
}

// Bake weights into exact MFMA B-fragment layout (bf16, BN-folded, oc>=8 zero):
// wB[(tap*2+cc)*64 + lane] = 8 bf16: B[k = hi*8+j][col = oc], k-channel = cc*32+hi*8+j
__global__ void repack_kernel(const float* __restrict__ conv_w,
                              const float* __restrict__ gamma,
                              const float* __restrict__ beta,
                              const float* __restrict__ mean,
                              const float* __restrict__ var,
                              unsigned short* __restrict__ wB,
                              float* __restrict__ bias)
{
    int tid = blockIdx.x * 256 + threadIdx.x;
    if (tid < 18 * 64) {
        int tc = tid >> 6;          // tap*2 + cc
        int lane = tid & 63;
        int tap = tc >> 1, cc = tc & 1;
        int oc = lane & 15, hi = lane >> 4;
        unsigned v[8];
#pragma unroll
        for (int j = 0; j < 8; ++j) {
            float w = 0.f;
            if (oc < 8) {
                int c = cc * 32 + hi * 8 + j;
                float scl = gamma[oc] * rsqrtf(var[oc] + 1e-5f);
                w = conv_w[((size_t)oc * CIN + c) * 9 + tap] * scl;
            }
            v[j] = f2bf(w);
        }
        uint4 pk;
        pk.x = v[0] | (v[1] << 16);
        pk.y = v[2] | (v[3] << 16);
        pk.z = v[4] | (v[5] << 16);
        pk.w = v[6] | (v[7] << 16);
        ((uint4*)wB)[tid] = pk;
    }
    if (tid < OCH) {
        float scl = gamma[tid] * rsqrtf(var[tid] + 1e-5f);
        bias[tid] = beta[tid] - mean[tid] * scl;
    }
}

// Zero only the uncovered border ring of each (b,t) OUTPUT plane.
__global__ void border_kernel(float* __restrict__ out)
{
    const int bt = blockIdx.x;          // 0..35
    const int t = bt % 9;
    const int i = t / 3, j = t % 3;
    float* pl = out + (size_t)bt * OHH * OWW;
    const int r0 = (i == 0) ? HH : 0;
    const int r1 = (i == 2) ? 1 : (OHH - 1);
    const int c0 = (j == 0) ? WW : 0;
    const int c1 = (j == 2) ? 1 : (OWW - 1);
    const int nrow = 2 * OWW;
    for (int idx = threadIdx.x; idx < 2 * OWW + 2 * OHH; idx += blockDim.x) {
        if (idx < nrow) {
            int r = (idx < OWW) ? r0 : r1;
            int c = (idx < OWW) ? idx : idx - OWW;
            pl[(size_t)r * OWW + c] = 0.f;
        } else {
            int k = idx - nrow;
            int c = (k < OHH) ? c0 : c1;
            int r = (k < OHH) ? k : k - OHH;
            pl[(size_t)r * OWW + c] = 0.f;
        }
    }
}

#define PACK1(VV, MK, SL, BUF) { \
    uint4 pk_; \
    pk_.x = f2bf(VV[0] * MK) | (f2bf(VV[1] * MK) << 16); \
    pk_.y = f2bf(VV[2] * MK) | (f2bf(VV[3] * MK) << 16); \
    pk_.z = f2bf(VV[4] * MK) | (f2bf(VV[5] * MK) << 16); \
    pk_.w = f2bf(VV[6] * MK) | (f2bf(VV[7] * MK) << 16); \
    (BUF)[SL] = pk_; }

// 72 MFMAs for one chunk from BUF using bwl[9].
#define MFMA_CHUNK(BUF) \
    _Pragma("unroll") for (int t = 0; t < 9; ++t) { \
        const int dh = t / 3, dw = t % 3; \
        _Pragma("unroll") for (int rr = 0; rr < 4; ++rr) { \
            const int fr = wv4 + rr + dh; \
            _Pragma("unroll") for (int cg = 0; cg < 2; ++cg) { \
                const int fc = cg * 16 + oc + dw; \
                const int pp = fr * FC + fc; \
                bf16x8 av = *reinterpret_cast<const bf16x8*>(&(BUF)[pp * 4 + (hi ^ ((pp >> 1) & 3))]); \
                acc[rr][cg] = __builtin_amdgcn_mfma_f32_16x16x32_bf16(av, bwl[t], acc[rr][cg], 0, 0, 0); \
            } } }

__global__ __launch_bounds__(NTHR, 2)   // (256,2): VGPR cap 256; tighter caps spill (r3/r14/r15)
void conv_mfma(const float* __restrict__ feature,
               const unsigned short* __restrict__ wB,
               const float* __restrict__ bias,
               float* __restrict__ out)
{
    __shared__ uint4 sA[NPOS * 4];   // chunk 0 tile, 39424 B
    __shared__ uint4 sB[NPOS * 4];   // chunk 1 tile, 39424 B

    // Bijective XCD swizzle (nwg = 3344 = 8*418): FETCH 707 -> 320 MB (r14/r16).
    const int lin = blockIdx.x;
    const int wg  = (lin & 7) * CPX + (lin >> 3);
    const int bx  = wg % GX;
    const int byz = wg / GX;
    const int by  = byz % GY;
    const int b   = byz / GY;

    const int tid  = threadIdx.x;
    const int wave = tid >> 6;
    const int lane = tid & 63;
    const int oc   = lane & 15;
    const int hi   = lane >> 4;
    const int wv4  = wave * 4;
    const int h0 = by * BH;
    const int w0 = bx * BW;

    const float* fb = feature + (size_t)b * CIN * HW;
    const int soct = tid & 3;
    const int p0   = tid >> 2;

    f32x4 acc[4][2];
#pragma unroll
    for (int rr = 0; rr < 4; ++rr)
#pragma unroll
        for (int cg = 0; cg < 2; ++cg) acc[rr][cg] = (f32x4)0.f;

    // ---- stage chunk 0 into sA: two lean 5-task passes (40-reg buffer) ----
    {
        const float* chbase = fb + (size_t)(soct * 8) * HW;
#pragma unroll 1
        for (int hf = 0; hf < 2; ++hf) {
            float v[5][8]; float mk5[5]; int sl5[5];
#pragma unroll
            for (int k = 0; k < 5; ++k) {
                int it = hf * 5 + k;
                int pos2 = p0 + it * 64; pos2 = (pos2 < NPOS) ? pos2 : (NPOS - 1);
                int fr2 = pos2 / FC; int fc2 = pos2 - fr2 * FC;
                int gh2 = h0 - 1 + fr2, gw2 = w0 - 1 + fc2;
                mk5[k] = (((unsigned)gh2 < (unsigned)HH) && ((unsigned)gw2 < (unsigned)WW)) ? 1.f : 0.f;
                sl5[k] = pos2 * 4 + (soct ^ ((pos2 >> 1) & 3));
                const float* sp2 = chbase + (min(max(gh2, 0), HH - 1) * WW + min(max(gw2, 0), WW - 1));
#pragma unroll
                for (int j = 0; j < 8; ++j) v[k][j] = sp2[(size_t)j * HW];
            }
#pragma unroll
            for (int k = 0; k < 5; ++k) PACK1(v[k], mk5[k], sl5[k], sA)
        }
    }
    __syncthreads();

    // ---- pipeline: issue ALL chunk-1 loads, then MFMA chunk 0, then pack ----
    float v1[NIT][8]; float mk1[NIT]; int sl1[NIT];
    {
        const float* chbase = fb + (size_t)(32 + soct * 8) * HW;
#pragma unroll
        for (int it = 0; it < NIT; ++it) {
            int pos2 = p0 + it * 64; pos2 = (pos2 < NPOS) ? pos2 : (NPOS - 1);
            int fr2 = pos2 / FC; int fc2 = pos2 - fr2 * FC;
            int gh2 = h0 - 1 + fr2, gw2 = w0 - 1 + fc2;
            mk1[it] = (((unsigned)gh2 < (unsigned)HH) && ((unsigned)gw2 < (unsigned)WW)) ? 1.f : 0.f;
            sl1[it] = pos2 * 4 + (soct ^ ((pos2 >> 1) & 3));
            const float* sp2 = chbase + (min(max(gh2, 0), HH - 1) * WW + min(max(gw2, 0), WW - 1));
#pragma unroll
            for (int j = 0; j < 8; ++j) v1[it][j] = sp2[(size_t)j * HW];
        }
    }
    __builtin_amdgcn_sched_barrier(0);   // keep the 80 loads issued above the MFMA phase

    {
        bf16x8 bwl[9];
#pragma unroll
        for (int t = 0; t < 9; ++t)
            bwl[t] = ((const bf16x8*)wB)[(t * 2 + 0) * 64 + lane];
        MFMA_CHUNK(sA)                   // chunk-1 loads in flight underneath
    }

#pragma unroll
    for (int it = 0; it < NIT; ++it) PACK1(v1[it], mk1[it], sl1[it], sB)
    __syncthreads();

    {
        bf16x8 bwl[9];
#pragma unroll
        for (int t = 0; t < 9; ++t)
            bwl[t] = ((const bf16x8*)wB)[(t * 2 + 1) * 64 + lane];
        MFMA_CHUNK(sB)
    }

    // ---- epilogue: bias, L1-normalize across oc (16-lane shfl), mid, scatter ----
    const float myb = (oc < 8) ? bias[oc] : 0.f;
    const int t = (oc < 8) ? ((oc < 4) ? oc : oc + 1) : 4;
    const bool dow = (oc <= 8);
    const int ii = t / 3, jj = t % 3;
    float* pl = out + ((size_t)(b * 9 + t) * OHH + ii) * OWW + jj;

#pragma unroll
    for (int rr = 0; rr < 4; ++rr) {
        const int h = h0 + wv4 + rr;
#pragma unroll
        for (int cg = 0; cg < 2; ++cg) {
#pragma unroll
            for (int reg = 0; reg < 4; ++reg) {
                float vv = acc[rr][cg][reg] + myb;   // lanes oc>=8: 0
                float av = fabsf(vv);
                float sv = vv;
                av += __shfl_xor(av, 1);  sv += __shfl_xor(sv, 1);
                av += __shfl_xor(av, 2);  sv += __shfl_xor(sv, 2);
                av += __shfl_xor(av, 4);  sv += __shfl_xor(sv, 4);
                av += __shfl_xor(av, 8);  sv += __shfl_xor(sv, 8);
                float inv = 1.0f / av;
                float val = (oc == 8) ? (1.0f - sv * inv) : (vv * inv);
                if (dow) {
                    int w = w0 + cg * 16 + hi * 4 + reg;
                    pl[(size_t)h * OWW + w] = val;
                }
            }
        }
    }
}

extern "C" void kernel_launch(void* const* d_in, const int* in_sizes, int n_in,
                              void* d_out, int out_size, void* d_ws, size_t ws_size,
                              hipStream_t stream) {
    const float* feature = (const float*)d_in[0];
    const float* conv_w  = (const float*)d_in[1];
    const float* gamma   = (const float*)d_in[2];
    const float* beta    = (const float*)d_in[3];
    const float* mean    = (const float*)d_in[4];
    const float* var     = (const float*)d_in[5];
    float* out = (float*)d_out;

    unsigned short* wB = (unsigned short*)d_ws;    // 18432 B
    float* bias = (float*)((char*)d_ws + 18432);   // 32 B

    border_kernel<<<BATCH * 9, 256, 0, stream>>>(out);
    repack_kernel<<<5, 256, 0, stream>>>(conv_w, gamma, beta, mean, var, wB, bias);
    conv_mfma<<<NWG, NTHR, 0, stream>>>(feature, wB, bias, out);
}